// Round 1
// baseline (2523.028 us; speedup 1.0000x reference)
//
#include <hip/hip_runtime.h>

// Problem constants (from reference): N=50000 nodes, E=600000 edges, D=128.
#define D 128

// ---------------------------------------------------------------------------
// Scatter: aggr[row[e]] += edge_attr[e]; aggr[col[e]] += edge_attr[e]
// 32 threads per edge, each handles one float4 (4 floats) -> 8 atomicAdds.
// ---------------------------------------------------------------------------
__global__ __launch_bounds__(256) void scatter_add_kernel(
    const float* __restrict__ edge_attr,
    const int* __restrict__ ei,   // [2, E] (row ptr = ei, col ptr = ei + E)
    float* __restrict__ aggr, int E) {
  long long gid = (long long)blockIdx.x * blockDim.x + threadIdx.x;
  int q = (int)(gid & 31);        // float4 slot within the 128-wide row
  long long e = gid >> 5;
  if (e >= E) return;
  float4 v = reinterpret_cast<const float4*>(edge_attr)[e * 32 + q];
  int r = ei[e];
  int c = ei[E + e];
  float* pr = aggr + (long long)r * D + q * 4;
  float* pc = aggr + (long long)c * D + q * 4;
  atomicAdd(pr + 0, v.x); atomicAdd(pr + 1, v.y);
  atomicAdd(pr + 2, v.z); atomicAdd(pr + 3, v.w);
  atomicAdd(pc + 0, v.x); atomicAdd(pc + 1, v.y);
  atomicAdd(pc + 2, v.z); atomicAdd(pc + 3, v.w);
}

// ---------------------------------------------------------------------------
// Fused MLP layer: out = act(A @ W + b), A = [x | aggr] (K=256) or h (K=128).
// Tile: 64 nodes x 128 cols per 256-thread block. Each thread: 8 nodes x 4
// cols accumulators. K streamed through LDS in chunks of 64.
// LDS = 16KB (A tile) + 32KB (W tile) = 48KB -> up to 3 blocks/CU.
// ---------------------------------------------------------------------------
template <int K, bool RELU>
__global__ __launch_bounds__(256) void mlp_layer(
    const float* __restrict__ A0,   // x (N x 128) or h (N x 128)
    const float* __restrict__ A1,   // aggr (N x 128); unused when K==128
    const float* __restrict__ W,    // K x 128 row-major
    const float* __restrict__ bias, // 128
    float* __restrict__ outp, int N) {
  constexpr int KC = 64;
  __shared__ float As[64][KC];
  __shared__ float Ws[KC][D];
  const int t = threadIdx.x;
  const int tx = t & 31;   // column group: cols 4*tx .. 4*tx+3
  const int ty = t >> 5;   // node group: rows 8*ty .. 8*ty+7
  const int row0 = blockIdx.x * 64;
  const int col = tx * 4;

  float acc[8][4];
  {
    float4 b = reinterpret_cast<const float4*>(bias)[tx];
#pragma unroll
    for (int i = 0; i < 8; ++i) {
      acc[i][0] = b.x; acc[i][1] = b.y; acc[i][2] = b.z; acc[i][3] = b.w;
    }
  }

  for (int kc = 0; kc < K; kc += KC) {
    // Load A tile: 64 rows x KC cols. 16 consecutive threads load one row.
#pragma unroll
    for (int p = 0; p < 4; ++p) {
      int r = p * 16 + (t >> 4);
      int c4 = (t & 15);
      int gk = kc + c4 * 4;
      int gr = row0 + r;
      float4 v = make_float4(0.f, 0.f, 0.f, 0.f);
      if (gr < N) {
        const float* src;
        if (K == 256) {
          src = (gk < 128) ? (A0 + (long long)gr * 128 + gk)
                           : (A1 + (long long)gr * 128 + (gk - 128));
        } else {
          src = A0 + (long long)gr * 128 + gk;
        }
        v = *reinterpret_cast<const float4*>(src);
      }
      *reinterpret_cast<float4*>(&As[r][c4 * 4]) = v;
    }
    // Load W tile: KC rows x 128 cols. 32 consecutive threads load one row.
#pragma unroll
    for (int p = 0; p < 8; ++p) {
      int r = p * 8 + (t >> 5);
      int c4 = (t & 31);
      float4 v = *reinterpret_cast<const float4*>(W + (long long)(kc + r) * D + c4 * 4);
      *reinterpret_cast<float4*>(&Ws[r][c4 * 4]) = v;
    }
    __syncthreads();

#pragma unroll
    for (int k4 = 0; k4 < KC / 4; ++k4) {
      float4 wv[4];
#pragma unroll
      for (int kk = 0; kk < 4; ++kk)
        wv[kk] = *reinterpret_cast<const float4*>(&Ws[k4 * 4 + kk][col]);
#pragma unroll
      for (int i = 0; i < 8; ++i) {
        float4 av = *reinterpret_cast<const float4*>(&As[ty * 8 + i][k4 * 4]);
        acc[i][0] += av.x * wv[0].x + av.y * wv[1].x + av.z * wv[2].x + av.w * wv[3].x;
        acc[i][1] += av.x * wv[0].y + av.y * wv[1].y + av.z * wv[2].y + av.w * wv[3].y;
        acc[i][2] += av.x * wv[0].z + av.y * wv[1].z + av.z * wv[2].z + av.w * wv[3].z;
        acc[i][3] += av.x * wv[0].w + av.y * wv[1].w + av.z * wv[2].w + av.w * wv[3].w;
      }
    }
    __syncthreads();
  }

#pragma unroll
  for (int i = 0; i < 8; ++i) {
    int gr = row0 + ty * 8 + i;
    if (gr < N) {
      float4 o = make_float4(acc[i][0], acc[i][1], acc[i][2], acc[i][3]);
      if (RELU) {
        o.x = fmaxf(o.x, 0.f); o.y = fmaxf(o.y, 0.f);
        o.z = fmaxf(o.z, 0.f); o.w = fmaxf(o.w, 0.f);
      }
      reinterpret_cast<float4*>(outp + (long long)gr * D)[tx] = o;
    }
  }
}

extern "C" void kernel_launch(void* const* d_in, const int* in_sizes, int n_in,
                              void* d_out, int out_size, void* d_ws, size_t ws_size,
                              hipStream_t stream) {
  const float* x         = (const float*)d_in[0];
  const int*   ei        = (const int*)d_in[1];   // [2, E] int32
  const float* edge_attr = (const float*)d_in[2];
  const float* W1        = (const float*)d_in[3];
  const float* b1        = (const float*)d_in[4];
  const float* W2        = (const float*)d_in[5];
  const float* b2        = (const float*)d_in[6];
  const int N = in_sizes[0] / D;
  const int E = in_sizes[2] / D;

  // Workspace layout: [aggr: N*D f32][h: N*D f32] = 51.2 MB total.
  float* aggr = (float*)d_ws;
  float* h    = aggr + (size_t)N * D;

  hipMemsetAsync(aggr, 0, (size_t)N * D * sizeof(float), stream);

  {
    long long total = (long long)E * 32;
    int blocks = (int)((total + 255) / 256);
    scatter_add_kernel<<<blocks, 256, 0, stream>>>(edge_attr, ei, aggr, E);
  }

  int gb = (N + 63) / 64;
  mlp_layer<256, true ><<<gb, 256, 0, stream>>>(x, aggr, W1, b1, h, N);
  mlp_layer<128, false><<<gb, 256, 0, stream>>>(h, nullptr, W2, b2, (float*)d_out, N);
}

// Round 2
// 899.978 us; speedup vs baseline: 2.8034x; 2.8034x over previous
//
#include <hip/hip_runtime.h>

// Problem constants (from reference): N=50000 nodes, E=600000 edges, D=128.
#define D 128

// ---------------------------------------------------------------------------
// CSR build phase A: degree histogram over both endpoints.
// Half-edge i in [0,2E): node = ei[i]; edge id = i % E.
// ---------------------------------------------------------------------------
__global__ __launch_bounds__(256) void degree_kernel(
    const int* __restrict__ ei, int* __restrict__ deg, int twoE) {
  int i = blockIdx.x * blockDim.x + threadIdx.x;
  if (i < twoE) atomicAdd(&deg[ei[i]], 1);
}

// ---------------------------------------------------------------------------
// CSR build phase B: single-block exclusive scan (Kogge-Stone in LDS, chunked).
// Writes both off[] (persistent starts) and cursor[] (mutable fill cursors).
// ---------------------------------------------------------------------------
__global__ __launch_bounds__(1024) void scan_kernel(
    const int* __restrict__ deg, int* __restrict__ off,
    int* __restrict__ cursor, int n) {
  __shared__ int sdata[1024];
  __shared__ int carry_s;
  int tid = threadIdx.x;
  if (tid == 0) carry_s = 0;
  __syncthreads();
  for (int base = 0; base < n; base += 1024) {
    int i = base + tid;
    int v = (i < n) ? deg[i] : 0;
    sdata[tid] = v;
    __syncthreads();
#pragma unroll
    for (int s = 1; s < 1024; s <<= 1) {
      int t = (tid >= s) ? sdata[tid - s] : 0;
      __syncthreads();
      sdata[tid] += t;
      __syncthreads();
    }
    int carry = carry_s;
    if (i < n) {
      int excl = carry + sdata[tid] - v;
      off[i] = excl;
      cursor[i] = excl;
    }
    __syncthreads();
    if (tid == 0) carry_s = carry + sdata[1023];
    __syncthreads();
  }
}

// ---------------------------------------------------------------------------
// CSR build phase C: scatter edge ids into per-node segments.
// ---------------------------------------------------------------------------
__global__ __launch_bounds__(256) void fill_kernel(
    const int* __restrict__ ei, int* __restrict__ cursor,
    int* __restrict__ elist, int E, int twoE) {
  int i = blockIdx.x * blockDim.x + threadIdx.x;
  if (i >= twoE) return;
  int node = ei[i];
  int e = (i < E) ? i : i - E;
  int pos = atomicAdd(&cursor[node], 1);
  elist[pos] = e;
}

// ---------------------------------------------------------------------------
// Gather: aggr[node][j] = sum over incident edges of edge_attr[e][j].
// One 128-thread block per node; thread j owns column j. Each edge row is a
// coalesced 512B read. Unroll-4 keeps 4 independent loads in flight.
// ---------------------------------------------------------------------------
__global__ __launch_bounds__(128) void gather_kernel(
    const float* __restrict__ edge_attr, const int* __restrict__ off,
    const int* __restrict__ deg, const int* __restrict__ elist,
    float* __restrict__ aggr, int N) {
  int node = blockIdx.x;
  int j = threadIdx.x;
  int s = off[node];
  int d = deg[node];
  float acc = 0.f;
  int k = 0;
  for (; k + 4 <= d; k += 4) {
    int e0 = elist[s + k + 0];
    int e1 = elist[s + k + 1];
    int e2 = elist[s + k + 2];
    int e3 = elist[s + k + 3];
    float v0 = edge_attr[(long long)e0 * D + j];
    float v1 = edge_attr[(long long)e1 * D + j];
    float v2 = edge_attr[(long long)e2 * D + j];
    float v3 = edge_attr[(long long)e3 * D + j];
    acc += (v0 + v1) + (v2 + v3);
  }
  for (; k < d; ++k) {
    int e = elist[s + k];
    acc += edge_attr[(long long)e * D + j];
  }
  aggr[(long long)node * D + j] = acc;
}

// ---------------------------------------------------------------------------
// Fused MLP layer: out = act(A @ W + b), A = [x | aggr] (K=256) or h (K=128).
// Tile: 64 nodes x 128 cols per 256-thread block. Each thread: 8 nodes x 4
// cols accumulators. K streamed through LDS in chunks of 64.
// LDS = 16KB (A tile) + 32KB (W tile) = 48KB -> up to 3 blocks/CU.
// ---------------------------------------------------------------------------
template <int K, bool RELU>
__global__ __launch_bounds__(256) void mlp_layer(
    const float* __restrict__ A0,   // x (N x 128) or h (N x 128)
    const float* __restrict__ A1,   // aggr (N x 128); unused when K==128
    const float* __restrict__ W,    // K x 128 row-major
    const float* __restrict__ bias, // 128
    float* __restrict__ outp, int N) {
  constexpr int KC = 64;
  __shared__ float As[64][KC];
  __shared__ float Ws[KC][D];
  const int t = threadIdx.x;
  const int tx = t & 31;   // column group: cols 4*tx .. 4*tx+3
  const int ty = t >> 5;   // node group: rows 8*ty .. 8*ty+7
  const int row0 = blockIdx.x * 64;
  const int col = tx * 4;

  float acc[8][4];
  {
    float4 b = reinterpret_cast<const float4*>(bias)[tx];
#pragma unroll
    for (int i = 0; i < 8; ++i) {
      acc[i][0] = b.x; acc[i][1] = b.y; acc[i][2] = b.z; acc[i][3] = b.w;
    }
  }

  for (int kc = 0; kc < K; kc += KC) {
    // Load A tile: 64 rows x KC cols. 16 consecutive threads load one row.
#pragma unroll
    for (int p = 0; p < 4; ++p) {
      int r = p * 16 + (t >> 4);
      int c4 = (t & 15);
      int gk = kc + c4 * 4;
      int gr = row0 + r;
      float4 v = make_float4(0.f, 0.f, 0.f, 0.f);
      if (gr < N) {
        const float* src;
        if (K == 256) {
          src = (gk < 128) ? (A0 + (long long)gr * 128 + gk)
                           : (A1 + (long long)gr * 128 + (gk - 128));
        } else {
          src = A0 + (long long)gr * 128 + gk;
        }
        v = *reinterpret_cast<const float4*>(src);
      }
      *reinterpret_cast<float4*>(&As[r][c4 * 4]) = v;
    }
    // Load W tile: KC rows x 128 cols. 32 consecutive threads load one row.
#pragma unroll
    for (int p = 0; p < 8; ++p) {
      int r = p * 8 + (t >> 5);
      int c4 = (t & 31);
      float4 v = *reinterpret_cast<const float4*>(W + (long long)(kc + r) * D + c4 * 4);
      *reinterpret_cast<float4*>(&Ws[r][c4 * 4]) = v;
    }
    __syncthreads();

#pragma unroll
    for (int k4 = 0; k4 < KC / 4; ++k4) {
      float4 wv[4];
#pragma unroll
      for (int kk = 0; kk < 4; ++kk)
        wv[kk] = *reinterpret_cast<const float4*>(&Ws[k4 * 4 + kk][col]);
#pragma unroll
      for (int i = 0; i < 8; ++i) {
        float4 av = *reinterpret_cast<const float4*>(&As[ty * 8 + i][k4 * 4]);
        acc[i][0] += av.x * wv[0].x + av.y * wv[1].x + av.z * wv[2].x + av.w * wv[3].x;
        acc[i][1] += av.x * wv[0].y + av.y * wv[1].y + av.z * wv[2].y + av.w * wv[3].y;
        acc[i][2] += av.x * wv[0].z + av.y * wv[1].z + av.z * wv[2].z + av.w * wv[3].z;
        acc[i][3] += av.x * wv[0].w + av.y * wv[1].w + av.z * wv[2].w + av.w * wv[3].w;
      }
    }
    __syncthreads();
  }

#pragma unroll
  for (int i = 0; i < 8; ++i) {
    int gr = row0 + ty * 8 + i;
    if (gr < N) {
      float4 o = make_float4(acc[i][0], acc[i][1], acc[i][2], acc[i][3]);
      if (RELU) {
        o.x = fmaxf(o.x, 0.f); o.y = fmaxf(o.y, 0.f);
        o.z = fmaxf(o.z, 0.f); o.w = fmaxf(o.w, 0.f);
      }
      reinterpret_cast<float4*>(outp + (long long)gr * D)[tx] = o;
    }
  }
}

extern "C" void kernel_launch(void* const* d_in, const int* in_sizes, int n_in,
                              void* d_out, int out_size, void* d_ws, size_t ws_size,
                              hipStream_t stream) {
  const float* x         = (const float*)d_in[0];
  const int*   ei        = (const int*)d_in[1];   // [2, E] int32
  const float* edge_attr = (const float*)d_in[2];
  const float* W1        = (const float*)d_in[3];
  const float* b1        = (const float*)d_in[4];
  const float* W2        = (const float*)d_in[5];
  const float* b2        = (const float*)d_in[6];
  const int N = in_sizes[0] / D;
  const int E = in_sizes[2] / D;
  const int twoE = 2 * E;

  // Workspace layout: [aggr: N*D f32][h: N*D f32] = 51.2 MB.
  // CSR metadata (deg/off/cursor: N ints each; elist: 2E ints ~ 5.4 MB total)
  // ALIASES the h region: it is fully consumed by gather_kernel before
  // mlp_layer<256> writes h (same stream => ordered).
  float* aggr = (float*)d_ws;
  float* h    = aggr + (size_t)N * D;
  int* deg    = (int*)h;
  int* off    = deg + N;
  int* cursor = off + N;
  int* elist  = cursor + N;

  hipMemsetAsync(deg, 0, (size_t)N * sizeof(int), stream);

  degree_kernel<<<(twoE + 255) / 256, 256, 0, stream>>>(ei, deg, twoE);
  scan_kernel<<<1, 1024, 0, stream>>>(deg, off, cursor, N);
  fill_kernel<<<(twoE + 255) / 256, 256, 0, stream>>>(ei, cursor, elist, E, twoE);
  gather_kernel<<<N, 128, 0, stream>>>(edge_attr, off, deg, elist, aggr, N);

  int gb = (N + 63) / 64;
  mlp_layer<256, true ><<<gb, 256, 0, stream>>>(x, aggr, W1, b1, h, N);
  mlp_layer<128, false><<<gb, 256, 0, stream>>>(h, nullptr, W2, b2, (float*)d_out, N);
}

// Round 3
// 819.092 us; speedup vs baseline: 3.0803x; 1.0988x over previous
//
#include <hip/hip_runtime.h>

// Problem constants (from reference): N=50000 nodes, E=600000 edges, D=128.
#define D 128

// ---------------------------------------------------------------------------
// CSR build phase A: degree histogram, int4-vectorized over both endpoints.
// ---------------------------------------------------------------------------
__global__ __launch_bounds__(256) void degree_kernel(
    const int* __restrict__ ei, int* __restrict__ deg, int twoE) {
  int i = blockIdx.x * blockDim.x + threadIdx.x;
  int base = i * 4;
  if (base + 3 < twoE) {
    int4 v = *reinterpret_cast<const int4*>(ei + base);
    atomicAdd(&deg[v.x], 1); atomicAdd(&deg[v.y], 1);
    atomicAdd(&deg[v.z], 1); atomicAdd(&deg[v.w], 1);
  } else {
    for (int j = base; j < twoE; ++j) atomicAdd(&deg[ei[j]], 1);
  }
}

// ---------------------------------------------------------------------------
// CSR build phase B: 3-phase exclusive scan over deg[0..n).
// B1: per-block (1024 elems) sums. B2: 1-wave scan of block sums (nb<=64).
// B3: per-block local scan + offset -> off[], cursor[].
// ---------------------------------------------------------------------------
__global__ __launch_bounds__(256) void scan_blocksum(
    const int* __restrict__ deg, int* __restrict__ partials, int n) {
  __shared__ int red[256];
  int t = threadIdx.x;
  int base = blockIdx.x * 1024 + t * 4;
  int s = 0;
#pragma unroll
  for (int j = 0; j < 4; ++j) {
    int i = base + j;
    s += (i < n) ? deg[i] : 0;
  }
  red[t] = s;
  __syncthreads();
#pragma unroll
  for (int w = 128; w > 0; w >>= 1) {
    if (t < w) red[t] += red[t + w];
    __syncthreads();
  }
  if (t == 0) partials[blockIdx.x] = red[0];
}

__global__ __launch_bounds__(64) void scan_partials(int* partials, int nb) {
  __shared__ int tmp[64];
  int t = threadIdx.x;
  int v = (t < nb) ? partials[t] : 0;
  tmp[t] = v;
  __syncthreads();
#pragma unroll
  for (int s = 1; s < 64; s <<= 1) {
    int a = (t >= s) ? tmp[t - s] : 0;
    __syncthreads();
    tmp[t] += a;
    __syncthreads();
  }
  if (t < nb) partials[t] = tmp[t] - v;  // exclusive
}

__global__ __launch_bounds__(256) void scan_final(
    const int* __restrict__ deg, const int* __restrict__ partials,
    int* __restrict__ off, int* __restrict__ cursor, int n) {
  __shared__ int red[256];
  int t = threadIdx.x;
  int base = blockIdx.x * 1024 + t * 4;
  int v[4];
#pragma unroll
  for (int j = 0; j < 4; ++j) v[j] = (base + j < n) ? deg[base + j] : 0;
  int tsum = v[0] + v[1] + v[2] + v[3];
  red[t] = tsum;
  __syncthreads();
#pragma unroll
  for (int s = 1; s < 256; s <<= 1) {
    int a = (t >= s) ? red[t - s] : 0;
    __syncthreads();
    red[t] += a;
    __syncthreads();
  }
  int e = red[t] - tsum + partials[blockIdx.x];
#pragma unroll
  for (int j = 0; j < 4; ++j) {
    if (base + j < n) { off[base + j] = e; cursor[base + j] = e; }
    e += v[j];
  }
}

// ---------------------------------------------------------------------------
// CSR build phase C: scatter edge ids into per-node segments.
// ---------------------------------------------------------------------------
__global__ __launch_bounds__(256) void fill_kernel(
    const int* __restrict__ ei, int* __restrict__ cursor,
    int* __restrict__ elist, int E, int twoE) {
  int i = blockIdx.x * blockDim.x + threadIdx.x;
  if (i >= twoE) return;
  int node = ei[i];
  int e = (i < E) ? i : i - E;
  int pos = atomicAdd(&cursor[node], 1);
  elist[pos] = e;
}

// ---------------------------------------------------------------------------
// Gather: aggr[node][j] = sum over incident edges of edge_attr[e][j].
// One 128-thread block per node; thread j owns column j.
// ---------------------------------------------------------------------------
__global__ __launch_bounds__(128) void gather_kernel(
    const float* __restrict__ edge_attr, const int* __restrict__ off,
    const int* __restrict__ deg, const int* __restrict__ elist,
    float* __restrict__ aggr, int N) {
  int node = blockIdx.x;
  int j = threadIdx.x;
  int s = off[node];
  int d = deg[node];
  float acc = 0.f;
  int k = 0;
  for (; k + 4 <= d; k += 4) {
    int e0 = elist[s + k + 0];
    int e1 = elist[s + k + 1];
    int e2 = elist[s + k + 2];
    int e3 = elist[s + k + 3];
    float v0 = edge_attr[(long long)e0 * D + j];
    float v1 = edge_attr[(long long)e1 * D + j];
    float v2 = edge_attr[(long long)e2 * D + j];
    float v3 = edge_attr[(long long)e3 * D + j];
    acc += (v0 + v1) + (v2 + v3);
  }
  for (; k < d; ++k) {
    int e = elist[s + k];
    acc += edge_attr[(long long)e * D + j];
  }
  aggr[(long long)node * D + j] = acc;
}

// ---------------------------------------------------------------------------
// Fused 2-layer MLP: out = (relu([x|aggr] @ W1 + b1)) @ W2 + b2.
// Block: 256 threads, 64 nodes. h-tile (64x128) kept in LDS between layers.
// LDS: Ws 32KB + union{As 16KB | Hs 32KB} = 64KB -> 2 blocks/CU.
// Each thread: 8 rows x 4 cols accumulators.
// ---------------------------------------------------------------------------
__global__ __launch_bounds__(256) void fused_mlp(
    const float* __restrict__ x, const float* __restrict__ aggr,
    const float* __restrict__ W1, const float* __restrict__ b1,
    const float* __restrict__ W2, const float* __restrict__ b2,
    float* __restrict__ outp, int N) {
  constexpr int KC = 64;
  __shared__ float Ws[KC][D];        // 32KB
  __shared__ float AsHs[64 * D];     // 32KB: As[64][64] in phase1, Hs[64][128] in phase2
  const int t = threadIdx.x;
  const int tx = t & 31;
  const int ty = t >> 5;
  const int row0 = blockIdx.x * 64;
  const int col = tx * 4;

  float acc[8][4];
  {
    float4 b = reinterpret_cast<const float4*>(b1)[tx];
#pragma unroll
    for (int i = 0; i < 8; ++i) {
      acc[i][0] = b.x; acc[i][1] = b.y; acc[i][2] = b.z; acc[i][3] = b.w;
    }
  }

  // ---- Layer 1: A = [x | aggr], K = 256 ----
  for (int kc = 0; kc < 256; kc += KC) {
    // A tile: 64 rows x 64 cols (As stride 64). 16 threads per row.
#pragma unroll
    for (int p = 0; p < 4; ++p) {
      int r = p * 16 + (t >> 4);
      int c4 = (t & 15);
      int gk = kc + c4 * 4;
      int gr = row0 + r;
      float4 v = make_float4(0.f, 0.f, 0.f, 0.f);
      if (gr < N) {
        const float* src = (gk < 128) ? (x + (long long)gr * 128 + gk)
                                      : (aggr + (long long)gr * 128 + (gk - 128));
        v = *reinterpret_cast<const float4*>(src);
      }
      *reinterpret_cast<float4*>(&AsHs[r * KC + c4 * 4]) = v;
    }
    // W tile: 64 rows x 128 cols.
#pragma unroll
    for (int p = 0; p < 8; ++p) {
      int r = p * 8 + (t >> 5);
      float4 v = *reinterpret_cast<const float4*>(W1 + (long long)(kc + r) * D + (t & 31) * 4);
      *reinterpret_cast<float4*>(&Ws[r][(t & 31) * 4]) = v;
    }
    __syncthreads();
#pragma unroll
    for (int k4 = 0; k4 < KC / 4; ++k4) {
      float4 wv[4];
#pragma unroll
      for (int kk = 0; kk < 4; ++kk)
        wv[kk] = *reinterpret_cast<const float4*>(&Ws[k4 * 4 + kk][col]);
#pragma unroll
      for (int i = 0; i < 8; ++i) {
        float4 av = *reinterpret_cast<const float4*>(&AsHs[(ty * 8 + i) * KC + k4 * 4]);
        acc[i][0] += av.x * wv[0].x + av.y * wv[1].x + av.z * wv[2].x + av.w * wv[3].x;
        acc[i][1] += av.x * wv[0].y + av.y * wv[1].y + av.z * wv[2].y + av.w * wv[3].y;
        acc[i][2] += av.x * wv[0].z + av.y * wv[1].z + av.z * wv[2].z + av.w * wv[3].z;
        acc[i][3] += av.x * wv[0].w + av.y * wv[1].w + av.z * wv[2].w + av.w * wv[3].w;
      }
    }
    __syncthreads();
  }

  // ReLU, stash h-tile in LDS (Hs stride 128, overlapping dead As region).
#pragma unroll
  for (int i = 0; i < 8; ++i) {
    float4 o = make_float4(fmaxf(acc[i][0], 0.f), fmaxf(acc[i][1], 0.f),
                           fmaxf(acc[i][2], 0.f), fmaxf(acc[i][3], 0.f));
    *reinterpret_cast<float4*>(&AsHs[(ty * 8 + i) * D + col]) = o;
  }

  // ---- Layer 2: A = Hs, K = 128 ----
  {
    float4 b = reinterpret_cast<const float4*>(b2)[tx];
#pragma unroll
    for (int i = 0; i < 8; ++i) {
      acc[i][0] = b.x; acc[i][1] = b.y; acc[i][2] = b.z; acc[i][3] = b.w;
    }
  }
  for (int kc = 0; kc < 128; kc += KC) {
#pragma unroll
    for (int p = 0; p < 8; ++p) {
      int r = p * 8 + (t >> 5);
      float4 v = *reinterpret_cast<const float4*>(W2 + (long long)(kc + r) * D + (t & 31) * 4);
      *reinterpret_cast<float4*>(&Ws[r][(t & 31) * 4]) = v;
    }
    __syncthreads();  // covers Hs writes (first iter) + Ws load
#pragma unroll
    for (int k4 = 0; k4 < KC / 4; ++k4) {
      float4 wv[4];
#pragma unroll
      for (int kk = 0; kk < 4; ++kk)
        wv[kk] = *reinterpret_cast<const float4*>(&Ws[k4 * 4 + kk][col]);
#pragma unroll
      for (int i = 0; i < 8; ++i) {
        float4 av = *reinterpret_cast<const float4*>(&AsHs[(ty * 8 + i) * D + kc + k4 * 4]);
        acc[i][0] += av.x * wv[0].x + av.y * wv[1].x + av.z * wv[2].x + av.w * wv[3].x;
        acc[i][1] += av.x * wv[0].y + av.y * wv[1].y + av.z * wv[2].y + av.w * wv[3].y;
        acc[i][2] += av.x * wv[0].z + av.y * wv[1].z + av.z * wv[2].z + av.w * wv[3].z;
        acc[i][3] += av.x * wv[0].w + av.y * wv[1].w + av.z * wv[2].w + av.w * wv[3].w;
      }
    }
    __syncthreads();
  }

#pragma unroll
  for (int i = 0; i < 8; ++i) {
    int gr = row0 + ty * 8 + i;
    if (gr < N) {
      float4 o = make_float4(acc[i][0], acc[i][1], acc[i][2], acc[i][3]);
      reinterpret_cast<float4*>(outp + (long long)gr * D)[tx] = o;
    }
  }
}

extern "C" void kernel_launch(void* const* d_in, const int* in_sizes, int n_in,
                              void* d_out, int out_size, void* d_ws, size_t ws_size,
                              hipStream_t stream) {
  const float* x         = (const float*)d_in[0];
  const int*   ei        = (const int*)d_in[1];   // [2, E] int32
  const float* edge_attr = (const float*)d_in[2];
  const float* W1        = (const float*)d_in[3];
  const float* b1        = (const float*)d_in[4];
  const float* W2        = (const float*)d_in[5];
  const float* b2        = (const float*)d_in[6];
  const int N = in_sizes[0] / D;
  const int E = in_sizes[2] / D;
  const int twoE = 2 * E;

  // Workspace: [aggr: N*D f32][deg N][off N][cursor N][partials 64][elist 2E]
  float* aggr   = (float*)d_ws;
  int* deg      = (int*)(aggr + (size_t)N * D);
  int* off      = deg + N;
  int* cursor   = off + N;
  int* partials = cursor + N;
  int* elist    = partials + 64;

  const int nb = (N + 1023) / 1024;  // scan blocks (49 for N=50000)

  hipMemsetAsync(deg, 0, (size_t)N * sizeof(int), stream);

  degree_kernel<<<(twoE / 4 + 255) / 256, 256, 0, stream>>>(ei, deg, twoE);
  scan_blocksum<<<nb, 256, 0, stream>>>(deg, partials, N);
  scan_partials<<<1, 64, 0, stream>>>(partials, nb);
  scan_final<<<nb, 256, 0, stream>>>(deg, partials, off, cursor, N);
  fill_kernel<<<(twoE + 255) / 256, 256, 0, stream>>>(ei, cursor, elist, E, twoE);
  gather_kernel<<<N, 128, 0, stream>>>(edge_attr, off, deg, elist, aggr, N);

  int gb = (N + 63) / 64;
  fused_mlp<<<gb, 256, 0, stream>>>(x, aggr, W1, b1, W2, b2, (float*)d_out, N);
}